// Round 4
// baseline (36.716 us; speedup 1.0000x reference)
//
#include <hip/hip_runtime.h>

static constexpr int kNodes = 100000;
static constexpr int kEdges = 1600000;
static constexpr int kD     = 128;

// Native clang vector types — accepted by __builtin_nontemporal_load/store
// (HIP_vector_type wrappers are not).
typedef float              fx4  __attribute__((ext_vector_type(4)));
typedef int                ix4  __attribute__((ext_vector_type(4)));
typedef unsigned long long ux2  __attribute__((ext_vector_type(2)));

// ---------------------------------------------------------------------------
// Phase 1: per-node partial dot products.
// h[n] = { emb[n]·W[0][0:128], emb[n]·W[1][0:128],
//          emb[n]·W[0][128:256], emb[n]·W[1][128:256] }
// 16 lanes per node, 8 columns per lane, W slices in registers (float4 loads),
// ~4 nodes per group via grid-stride (amortizes W load + register setup).
// Reduction: 5-shuffle transpose-reduce -> lane j of each 16-lane group ends
// with output j (j<4), stored as a contiguous 4-float chunk.
// ---------------------------------------------------------------------------
__global__ __launch_bounds__(256) void node_pre(const float* __restrict__ emb,
                                                const float* __restrict__ W,
                                                float* __restrict__ h) {
    const int l  = threadIdx.x & 15;   // lane within 16-group
    const int c0 = l * 8;

    fx4 w0a = *(const fx4*)&W[c0],       w0b = *(const fx4*)&W[c0 + 4];
    fx4 w1a = *(const fx4*)&W[256 + c0], w1b = *(const fx4*)&W[256 + c0 + 4];
    fx4 w2a = *(const fx4*)&W[128 + c0], w2b = *(const fx4*)&W[128 + c0 + 4];
    fx4 w3a = *(const fx4*)&W[384 + c0], w3b = *(const fx4*)&W[384 + c0 + 4];

    const int group   = (blockIdx.x * blockDim.x + threadIdx.x) >> 4;
    const int ngroups = (gridDim.x * blockDim.x) >> 4;

    for (int n = group; n < kNodes; n += ngroups) {
        const fx4* row = (const fx4*)(emb + (size_t)n * kD + c0);
        fx4 ea = __builtin_nontemporal_load(row);       // read-once stream
        fx4 eb = __builtin_nontemporal_load(row + 1);

        float p0 = ea.x*w0a.x + ea.y*w0a.y + ea.z*w0a.z + ea.w*w0a.w
                 + eb.x*w0b.x + eb.y*w0b.y + eb.z*w0b.z + eb.w*w0b.w;
        float p1 = ea.x*w1a.x + ea.y*w1a.y + ea.z*w1a.z + ea.w*w1a.w
                 + eb.x*w1b.x + eb.y*w1b.y + eb.z*w1b.z + eb.w*w1b.w;
        float p2 = ea.x*w2a.x + ea.y*w2a.y + ea.z*w2a.z + ea.w*w2a.w
                 + eb.x*w2b.x + eb.y*w2b.y + eb.z*w2b.z + eb.w*w2b.w;
        float p3 = ea.x*w3a.x + ea.y*w3a.y + ea.z*w3a.z + ea.w*w3a.w
                 + eb.x*w3b.x + eb.y*w3b.y + eb.z*w3b.z + eb.w*w3b.w;

        // --- 5-shuffle transpose-reduce over the 16-lane group ---
        float sendU = (l & 1) ? p0 : p1;
        float keepU = (l & 1) ? p1 : p0;
        float u = keepU + __shfl_xor(sendU, 1);
        float sendW = (l & 1) ? p2 : p3;
        float keepW = (l & 1) ? p3 : p2;
        float w = keepW + __shfl_xor(sendW, 1);
        float sendX = (l & 2) ? u : w;
        float keepX = (l & 2) ? w : u;
        float x = keepX + __shfl_xor(sendX, 2);
        x += __shfl_xor(x, 4);
        x += __shfl_xor(x, 8);

        if (l < 4) h[n * 4 + l] = x;   // contiguous 16B per group
    }
}

// ---------------------------------------------------------------------------
// Phase 2: 4 edges per thread. In-wave dtype detection (no extra kernel):
// every wave reads ei64[lane]; random indices < 100000 make an all-zero
// high-word pattern impossible for the int32-pair layout.
// Gathers 16B h-entries (1.6 MB table, L2-resident); streamed index loads and
// output stores are nontemporal to keep h cached.
// ---------------------------------------------------------------------------
__global__ __launch_bounds__(256) void edge_attn(const void* __restrict__ eiv,
                                                 const float* __restrict__ h,
                                                 const float* __restrict__ b,
                                                 float* __restrict__ out) {
    const unsigned long long* ei64 = (const unsigned long long*)eiv;
    unsigned long long hi = ei64[threadIdx.x & 63] >> 32;
    const bool is64 = (__ballot(hi != 0ull) == 0ull);

    const int e4 = blockIdx.x * blockDim.x + threadIdx.x;   // quad index
    if (e4 >= kEdges / 4) return;

    int r[4], c[4];
    if (is64) {
        const ux2* rr = (const ux2*)ei64;
        const ux2* cc = (const ux2*)(ei64 + kEdges);
        ux2 ra = __builtin_nontemporal_load(&rr[2 * e4]);
        ux2 rb = __builtin_nontemporal_load(&rr[2 * e4 + 1]);
        ux2 ca = __builtin_nontemporal_load(&cc[2 * e4]);
        ux2 cb = __builtin_nontemporal_load(&cc[2 * e4 + 1]);
        r[0] = (int)ra.x; r[1] = (int)ra.y; r[2] = (int)rb.x; r[3] = (int)rb.y;
        c[0] = (int)ca.x; c[1] = (int)ca.y; c[2] = (int)cb.x; c[3] = (int)cb.y;
    } else {
        const ix4* rr = (const ix4*)eiv;
        const ix4* cc = (const ix4*)((const int*)eiv + kEdges);
        ix4 ra = __builtin_nontemporal_load(&rr[e4]);
        ix4 ca = __builtin_nontemporal_load(&cc[e4]);
        r[0] = ra.x; r[1] = ra.y; r[2] = ra.z; r[3] = ra.w;
        c[0] = ca.x; c[1] = ca.y; c[2] = ca.z; c[3] = ca.w;
    }

    const fx4* h4 = (const fx4*)h;
    const float b0 = b[0], b1 = b[1];

    float res[8];
#pragma unroll
    for (int k = 0; k < 4; ++k) {
        fx4 hr = h4[r[k]];
        fx4 hc = h4[c[k]];
        float s0 = hr.x + hc.z + b0;
        float s1 = hr.y + hc.w + b1;
        float m  = fmaxf(s0, s1);
        float x0 = __expf(s0 - m);
        float x1 = __expf(s1 - m);
        float inv = 1.0f / (x0 + x1);
        res[2*k]     = x0 * inv;
        res[2*k + 1] = x1 * inv;
    }

    fx4* o4 = (fx4*)out;
    fx4 oa = {res[0], res[1], res[2], res[3]};
    fx4 ob = {res[4], res[5], res[6], res[7]};
    __builtin_nontemporal_store(oa, &o4[2 * e4]);
    __builtin_nontemporal_store(ob, &o4[2 * e4 + 1]);
}

extern "C" void kernel_launch(void* const* d_in, const int* in_sizes, int n_in,
                              void* d_out, int out_size, void* d_ws, size_t ws_size,
                              hipStream_t stream) {
    const float* emb = (const float*)d_in[0];
    const void*  ei  = d_in[1];
    const float* W   = (const float*)d_in[2];
    const float* b   = (const float*)d_in[3];
    float* out = (float*)d_out;

    float* h = (float*)d_ws;   // 1.6 MB node table, 16B-aligned

    // ~4 nodes per 16-lane group (grid-stride)
    node_pre<<<(kNodes * 16 / 4 + 255) / 256, 256, 0, stream>>>(emb, W, h);

    // 4 edges per thread
    edge_attn<<<(kEdges / 4 + 255) / 256, 256, 0, stream>>>(ei, h, b, out);
}